// Round 5
// baseline (392.265 us; speedup 1.0000x reference)
//
#include <hip/hip_runtime.h>

// GraphPooling: out[v] = mean over in-neighbors of h[src], else h[v] if deg==0.
// 65536 nodes x 64 f32 features, E = 1,048,576 edges.
//
// All-LDS-atomic two-level bucket pipeline (global atomics are memory-side on
// gfx950: 1M atomics showed up as 34.7 MB WRITE_SIZE / 42 us in round 4).
//   k_hist      : per-block LDS hist over 1024 buckets (bucket = dst>>6)
//   k_scanbuck  : exclusive scan across the 128 blocks, per bucket (in-place)
//   k_scantot   : exclusive scan of 1024 bucket totals -> bases
//   k_partition : LDS-cursor scatter of packed (src, dst&63) pairs
//   k_gather    : one block per bucket; LDS accum[64][65] f32 + LDS deg;
//                 wave-uniform shfl broadcast, 4-edge-parallel float4 gathers
// No hipMemsetAsync, no global atomics, ws = 4.52 MB.

#define NBUCK 1024
#define NPBLK 128
#define FDIM 64

__global__ void k_hist(const int* __restrict__ dst,
                       unsigned int* __restrict__ blockhist, int E, int epb) {
    __shared__ unsigned int hist[NBUCK];
    int t = threadIdx.x;
    for (int i = t; i < NBUCK; i += 256) hist[i] = 0;
    __syncthreads();
    int base = blockIdx.x * epb;
    for (int i = 0; i < epb; i += 256) {
        int e = base + i + t;
        if (e < E) atomicAdd(&hist[((unsigned)dst[e]) >> 6], 1u);
    }
    __syncthreads();
    for (int i = t; i < NBUCK; i += 256)
        blockhist[(size_t)blockIdx.x * NBUCK + i] = hist[i];
}

// One block (128 threads) per bucket: exclusive scan over the 128 block
// counts of this bucket, in place; write the bucket total.
__global__ void k_scanbuck(unsigned int* __restrict__ blockhist,
                           unsigned int* __restrict__ buckettotal) {
    int b = blockIdx.x;
    int t = threadIdx.x;              // 0..127, two full waves
    int lane = t & 63, wid = t >> 6;
    unsigned int v = blockhist[(size_t)t * NBUCK + b];
    unsigned int x = v;
    #pragma unroll
    for (int off = 1; off < 64; off <<= 1) {
        unsigned int y = __shfl_up(x, off);
        if (lane >= off) x += y;
    }
    __shared__ unsigned int ws[2];
    if (lane == 63) ws[wid] = x;
    __syncthreads();
    unsigned int add = (wid == 1) ? ws[0] : 0u;
    blockhist[(size_t)t * NBUCK + b] = add + x - v;   // exclusive prefix
    if (t == 127) buckettotal[b] = add + x;           // inclusive total
}

// Single block, 1024 threads: exclusive scan of bucket totals -> bases.
__global__ void k_scantot(const unsigned int* __restrict__ buckettotal,
                          unsigned int* __restrict__ bucketbase) {
    int t = threadIdx.x;
    int lane = t & 63, wid = t >> 6;   // 16 waves
    unsigned int v = buckettotal[t];
    unsigned int x = v;
    #pragma unroll
    for (int off = 1; off < 64; off <<= 1) {
        unsigned int y = __shfl_up(x, off);
        if (lane >= off) x += y;
    }
    __shared__ unsigned int wsum[16];
    if (lane == 63) wsum[wid] = x;
    __syncthreads();
    if (wid == 0) {                    // full-wave 16-elem scan (no divergence)
        unsigned int w = (lane < 16) ? wsum[lane] : 0u;
        #pragma unroll
        for (int off = 1; off < 16; off <<= 1) {
            unsigned int y = __shfl_up(w, off);
            if (lane >= off) w += y;
        }
        if (lane < 16) wsum[lane] = w;
    }
    __syncthreads();
    unsigned int wpre = wid ? wsum[wid - 1] : 0u;
    bucketbase[t] = wpre + x - v;
}

// Scatter edges into bucket order; pos from LDS cursors (no global atomics).
__global__ void k_partition(const int* __restrict__ src,
                            const int* __restrict__ dst,
                            const unsigned int* __restrict__ blockhist,
                            const unsigned int* __restrict__ bucketbase,
                            unsigned int* __restrict__ pairs, int E, int epb) {
    __shared__ unsigned int cursor[NBUCK];
    int t = threadIdx.x;
    for (int i = t; i < NBUCK; i += 256)
        cursor[i] = bucketbase[i] + blockhist[(size_t)blockIdx.x * NBUCK + i];
    __syncthreads();
    int base = blockIdx.x * epb;
    for (int i = 0; i < epb; i += 256) {
        int e = base + i + t;
        if (e < E) {
            unsigned int d = (unsigned)dst[e];
            unsigned int s = (unsigned)src[e];
            unsigned int pos = atomicAdd(&cursor[d >> 6], 1u);
            pairs[pos] = s | ((d & 63u) << 16);
        }
    }
}

// One block (4 waves) per bucket of 64 nodes. LDS float accumulation with
// padded stride 65 (bank-spread), LDS degree counters. Wave-uniform trip
// counts around every __shfl (round-3 lesson).
__global__ void k_gather(const float* __restrict__ h,
                         const unsigned int* __restrict__ pairs,
                         const unsigned int* __restrict__ bucketbase,
                         const unsigned int* __restrict__ buckettotal,
                         float* __restrict__ out) {
    __shared__ float accum[64 * 65];
    __shared__ unsigned int degl[64];
    int t = threadIdx.x;
    for (int i = t; i < 64 * 65; i += 256) accum[i] = 0.0f;
    if (t < 64) degl[t] = 0u;
    __syncthreads();

    int b = blockIdx.x;
    unsigned int seg = bucketbase[b];
    unsigned int cnt = buckettotal[b];
    int lane = t & 63, w = t >> 6;
    int egrp = lane >> 4, fq = lane & 15;
    const float4* h4 = (const float4*)h;

    for (unsigned int cb = (unsigned)w * 64u; cb < cnt; cb += 256u) {
        int chunk = (int)min(64u, cnt - cb);            // wave-uniform
        unsigned int pr = 0u;
        if (lane < chunk) {
            pr = pairs[seg + cb + lane];
            atomicAdd(&degl[pr >> 16], 1u);
        }
        int nit = (chunk + 3) >> 2;                     // wave-uniform
        for (int it = 0; it < nit; ++it) {
            int j = it * 4 + egrp;
            unsigned int pj = __shfl(pr, (j < chunk) ? j : 0);  // all lanes active
            unsigned int sj = pj & 0xFFFFu;
            unsigned int dj = pj >> 16;
            float4 m = h4[(size_t)sj * 16 + fq];
            if (j < chunk) {
                float* row = &accum[dj * 65 + fq * 4];
                atomicAdd(&row[0], m.x);
                atomicAdd(&row[1], m.y);
                atomicAdd(&row[2], m.z);
                atomicAdd(&row[3], m.w);
            }
        }
    }
    __syncthreads();

    // Finalize: 4 float4 per thread covers 64 nodes x 16 float4.
    float4* out4 = (float4*)out;
    for (int rep = 0; rep < 4; ++rep) {
        int fi = rep * 256 + t;
        int n = fi >> 4, q = fi & 15;
        unsigned int dgn = degl[n];
        size_t oi = ((size_t)b * 64 + n) * 16 + q;
        float4 r;
        if (dgn > 0u) {
            float inv = 1.0f / (float)dgn;
            const float* row = &accum[n * 65 + q * 4];
            r = make_float4(row[0] * inv, row[1] * inv, row[2] * inv, row[3] * inv);
        } else {
            r = h4[oi];
        }
        out4[oi] = r;
    }
}

extern "C" void kernel_launch(void* const* d_in, const int* in_sizes, int n_in,
                              void* d_out, int out_size, void* d_ws, size_t ws_size,
                              hipStream_t stream) {
    const float* h = (const float*)d_in[0];
    const int* src = (const int*)d_in[1];
    const int* dst = (const int*)d_in[2];
    float* out = (float*)d_out;
    int E = in_sizes[1];

    // ws layout (4.52 MB): blockhist 512 KB | buckettotal 4 KB | bucketbase 4 KB | pairs 4 MB
    unsigned int* blockhist   = (unsigned int*)d_ws;
    unsigned int* buckettotal = blockhist + (size_t)NPBLK * NBUCK;
    unsigned int* bucketbase  = buckettotal + NBUCK;
    unsigned int* pairs       = bucketbase + NBUCK;

    int epb = ((E + NPBLK - 1) / NPBLK + 255) & ~255;   // edges per partition block

    k_hist<<<NPBLK, 256, 0, stream>>>(dst, blockhist, E, epb);
    k_scanbuck<<<NBUCK, 128, 0, stream>>>(blockhist, buckettotal);
    k_scantot<<<1, 1024, 0, stream>>>(buckettotal, bucketbase);
    k_partition<<<NPBLK, 256, 0, stream>>>(src, dst, blockhist, bucketbase, pairs, E, epb);
    k_gather<<<NBUCK, 256, 0, stream>>>(h, pairs, bucketbase, buckettotal, out);
}

// Round 6
// 82.256 us; speedup vs baseline: 4.7688x; 4.7688x over previous
//
#include <hip/hip_runtime.h>

// GraphPooling: out[v] = mean over in-neighbors of h[src], else h[v] if deg==0.
// 65536 nodes x 64 f32 features, E = 1,048,576 edges.
//
// Bucket pipeline, zero global atomics, zero memsets:
//   k_hist      : per-block LDS hist over 1024 buckets (bucket = dst>>6)
//   k_scanbuck  : exclusive scan across the 128 blocks, per bucket
//   k_scantot   : exclusive scan of 1024 bucket totals -> bases
//   k_partition : LDS-cursor scatter of packed (src:16, dst&63:16) pairs
//   k_gather3   : per-bucket LDS counting sort (64 bins) + wave-per-16-nodes
//                 register-accumulating segment gather (round-4 pattern).
// Round-5 lesson: NO LDS float atomics for accumulation (64M ds_add = 359 us).

#define NBUCK 1024
#define NPBLK 128
#define BUCKCAP 2048   // max edges per bucket (avg 1024, ~5 sigma = 1200)

__global__ void k_hist(const int* __restrict__ dst,
                       unsigned int* __restrict__ blockhist, int E, int epb) {
    __shared__ unsigned int hist[NBUCK];
    int t = threadIdx.x;
    for (int i = t; i < NBUCK; i += 256) hist[i] = 0;
    __syncthreads();
    int base = blockIdx.x * epb;
    for (int i = 0; i < epb; i += 256) {
        int e = base + i + t;
        if (e < E) atomicAdd(&hist[((unsigned)dst[e]) >> 6], 1u);
    }
    __syncthreads();
    for (int i = t; i < NBUCK; i += 256)
        blockhist[(size_t)blockIdx.x * NBUCK + i] = hist[i];
}

// One block (128 threads) per bucket: exclusive scan over the 128 block
// counts of this bucket, in place; write the bucket total.
__global__ void k_scanbuck(unsigned int* __restrict__ blockhist,
                           unsigned int* __restrict__ buckettotal) {
    int b = blockIdx.x;
    int t = threadIdx.x;              // 0..127, two full waves
    int lane = t & 63, wid = t >> 6;
    unsigned int v = blockhist[(size_t)t * NBUCK + b];
    unsigned int x = v;
    #pragma unroll
    for (int off = 1; off < 64; off <<= 1) {
        unsigned int y = __shfl_up(x, off);
        if (lane >= off) x += y;
    }
    __shared__ unsigned int ws[2];
    if (lane == 63) ws[wid] = x;
    __syncthreads();
    unsigned int add = (wid == 1) ? ws[0] : 0u;
    blockhist[(size_t)t * NBUCK + b] = add + x - v;   // exclusive prefix
    if (t == 127) buckettotal[b] = add + x;           // inclusive total
}

// Single block, 1024 threads: exclusive scan of bucket totals -> bases.
__global__ void k_scantot(const unsigned int* __restrict__ buckettotal,
                          unsigned int* __restrict__ bucketbase) {
    int t = threadIdx.x;
    int lane = t & 63, wid = t >> 6;   // 16 waves
    unsigned int v = buckettotal[t];
    unsigned int x = v;
    #pragma unroll
    for (int off = 1; off < 64; off <<= 1) {
        unsigned int y = __shfl_up(x, off);
        if (lane >= off) x += y;
    }
    __shared__ unsigned int wsum[16];
    if (lane == 63) wsum[wid] = x;
    __syncthreads();
    if (wid == 0) {                    // full-wave 16-elem scan (no divergence)
        unsigned int w = (lane < 16) ? wsum[lane] : 0u;
        #pragma unroll
        for (int off = 1; off < 16; off <<= 1) {
            unsigned int y = __shfl_up(w, off);
            if (lane >= off) w += y;
        }
        if (lane < 16) wsum[lane] = w;
    }
    __syncthreads();
    unsigned int wpre = wid ? wsum[wid - 1] : 0u;
    bucketbase[t] = wpre + x - v;
}

// Scatter edges into bucket order; pos from LDS cursors (no global atomics).
__global__ void k_partition(const int* __restrict__ src,
                            const int* __restrict__ dst,
                            const unsigned int* __restrict__ blockhist,
                            const unsigned int* __restrict__ bucketbase,
                            unsigned int* __restrict__ pairs, int E, int epb) {
    __shared__ unsigned int cursor[NBUCK];
    int t = threadIdx.x;
    for (int i = t; i < NBUCK; i += 256)
        cursor[i] = bucketbase[i] + blockhist[(size_t)blockIdx.x * NBUCK + i];
    __syncthreads();
    int base = blockIdx.x * epb;
    for (int i = 0; i < epb; i += 256) {
        int e = base + i + t;
        if (e < E) {
            unsigned int d = (unsigned)dst[e];
            unsigned int s = (unsigned)src[e];
            unsigned int pos = atomicAdd(&cursor[d >> 6], 1u);
            pairs[pos] = s | ((d & 63u) << 16);
        }
    }
}

// One block (4 waves) per bucket of 64 nodes. LDS counting sort into per-node
// segments (u16 src), then each wave gathers 16 nodes with register float4
// accumulation. Wave-uniform trip counts around every __shfl (round-3 lesson).
__global__ __launch_bounds__(256) void k_gather3(
        const float* __restrict__ h,
        const unsigned int* __restrict__ pairs,
        const unsigned int* __restrict__ bucketbase,
        const unsigned int* __restrict__ buckettotal,
        float* __restrict__ out) {
    __shared__ unsigned int pairbuf[BUCKCAP];
    __shared__ unsigned short ssrc[BUCKCAP];
    __shared__ unsigned int hist[64], offl[64], cur[64];
    int t = threadIdx.x;
    int b = blockIdx.x;
    unsigned int seg = bucketbase[b];
    unsigned int cnt = min(buckettotal[b], (unsigned)BUCKCAP);  // safety clamp

    if (t < 64) hist[t] = 0u;
    __syncthreads();

    // Load pairs (coalesced) + per-node LDS hist.
    for (unsigned int i = t; i < cnt; i += 256u) {
        unsigned int p = pairs[seg + i];
        pairbuf[i] = p;
        atomicAdd(&hist[p >> 16], 1u);
    }
    __syncthreads();

    // Exclusive scan of the 64 node counts on wave 0 (full wave, no divergence).
    if (t < 64) {
        unsigned int v = hist[t];
        unsigned int x = v;
        #pragma unroll
        for (int off = 1; off < 64; off <<= 1) {
            unsigned int y = __shfl_up(x, off);
            if (t >= off) x += y;
        }
        offl[t] = x - v;
        cur[t]  = x - v;
    }
    __syncthreads();

    // LDS->LDS scatter into per-node sorted order (u16 src payload).
    for (unsigned int i = t; i < cnt; i += 256u) {
        unsigned int p = pairbuf[i];
        unsigned int pos = atomicAdd(&cur[p >> 16], 1u);
        ssrc[pos] = (unsigned short)(p & 0xFFFFu);
    }
    __syncthreads();

    // Gather: wave w handles nodes w*16 .. w*16+15.
    int lane = t & 63, w = t >> 6;
    int egrp = lane >> 4, fq = lane & 15;
    const float4* h4 = (const float4*)h;
    float4* out4 = (float4*)out;

    for (int ni = 0; ni < 16; ++ni) {
        int n = w * 16 + ni;
        unsigned int start = offl[n];
        unsigned int dg = hist[n];
        float4 acc = make_float4(0.f, 0.f, 0.f, 0.f);
        for (unsigned int base = 0; base < dg; base += 64u) {
            int chunk = (int)min(64u, dg - base);           // wave-uniform
            int sidx = (lane < chunk) ? (int)ssrc[start + base + lane] : 0;
            int nit = (chunk + 3) >> 2;                     // wave-uniform
            for (int it = 0; it < nit; ++it) {
                int j = it * 4 + egrp;
                int s = __shfl(sidx, (j < chunk) ? j : 0);  // all lanes active
                float4 m = h4[(size_t)s * 16 + fq];
                if (j < chunk) {
                    acc.x += m.x; acc.y += m.y; acc.z += m.z; acc.w += m.w;
                }
            }
        }
        #pragma unroll
        for (int k = 16; k <= 32; k <<= 1) {
            acc.x += __shfl_xor(acc.x, k);
            acc.y += __shfl_xor(acc.y, k);
            acc.z += __shfl_xor(acc.z, k);
            acc.w += __shfl_xor(acc.w, k);
        }
        if (lane < 16) {
            size_t oi = ((size_t)b * 64 + n) * 16 + fq;
            float4 r;
            if (dg > 0u) {
                float inv = 1.0f / (float)dg;
                r = make_float4(acc.x * inv, acc.y * inv, acc.z * inv, acc.w * inv);
            } else {
                r = h4[oi];
            }
            out4[oi] = r;
        }
    }
}

extern "C" void kernel_launch(void* const* d_in, const int* in_sizes, int n_in,
                              void* d_out, int out_size, void* d_ws, size_t ws_size,
                              hipStream_t stream) {
    const float* h = (const float*)d_in[0];
    const int* src = (const int*)d_in[1];
    const int* dst = (const int*)d_in[2];
    float* out = (float*)d_out;
    int E = in_sizes[1];

    // ws layout (4.52 MB): blockhist 512 KB | buckettotal 4 KB | bucketbase 4 KB | pairs 4 MB
    unsigned int* blockhist   = (unsigned int*)d_ws;
    unsigned int* buckettotal = blockhist + (size_t)NPBLK * NBUCK;
    unsigned int* bucketbase  = buckettotal + NBUCK;
    unsigned int* pairs       = bucketbase + NBUCK;

    int epb = ((E + NPBLK - 1) / NPBLK + 255) & ~255;   // edges per partition block

    k_hist<<<NPBLK, 256, 0, stream>>>(dst, blockhist, E, epb);
    k_scanbuck<<<NBUCK, 128, 0, stream>>>(blockhist, buckettotal);
    k_scantot<<<1, 1024, 0, stream>>>(buckettotal, bucketbase);
    k_partition<<<NPBLK, 256, 0, stream>>>(src, dst, blockhist, bucketbase, pairs, E, epb);
    k_gather3<<<NBUCK, 256, 0, stream>>>(h, pairs, bucketbase, buckettotal, out);
}

// Round 7
// 74.982 us; speedup vs baseline: 5.2314x; 1.0970x over previous
//
#include <hip/hip_runtime.h>

// GraphPooling: out[v] = mean over in-neighbors of h[src], else h[v] if deg==0.
// 65536 nodes x 64 f32 features, E = 1,048,576 edges.
//
// Bucket pipeline, zero global atomics, zero memsets:
//   k_cvt       : f32 h -> bf16 copy (RNE) in ws; gather reads 128 B/edge
//   k_hist      : per-block LDS hist over 2048 buckets (bucket = dst>>5)
//   k_scanbuck  : exclusive scan across the 256 blocks, per bucket
//   k_scantot   : exclusive scan of 2048 bucket totals -> bases
//   k_partition : LDS-cursor scatter of packed (src:16, dst&31:16) pairs
//   k_gather3   : per-bucket LDS counting sort (32 bins) + wave-per-8-nodes
//                 register-accumulating gather (f32 acc), 8 blocks/CU.
// deg==0 fallback always copies the f32 original (exact).
// Round-5 lesson: no LDS float atomics. Round-3 lesson: wave-uniform shfl.

#define NBUCK 2048     // 32 nodes per bucket
#define NPBLK 256
#define BUCKCAP 1024   // mean 512, sigma ~23 -> 22-sigma headroom

__global__ void k_cvt(const float* __restrict__ h,
                      uint4* __restrict__ hbf, int n8) {
    int i = blockIdx.x * blockDim.x + threadIdx.x;
    if (i >= n8) return;
    const float4* h4 = (const float4*)h;
    float4 a = h4[2 * i], b = h4[2 * i + 1];
    auto pk = [](float lo, float hi) {
        unsigned int ul = __float_as_uint(lo), uh = __float_as_uint(hi);
        unsigned int rl = (ul + 0x7FFFu + ((ul >> 16) & 1u)) >> 16;
        unsigned int rh = (uh + 0x7FFFu + ((uh >> 16) & 1u)) & 0xFFFF0000u;
        return rl | rh;
    };
    hbf[i] = make_uint4(pk(a.x, a.y), pk(a.z, a.w), pk(b.x, b.y), pk(b.z, b.w));
}

__global__ void k_hist(const int* __restrict__ dst,
                       unsigned int* __restrict__ blockhist, int E, int epb) {
    __shared__ unsigned int hist[NBUCK];
    int t = threadIdx.x;
    for (int i = t; i < NBUCK; i += 256) hist[i] = 0;
    __syncthreads();
    int base = blockIdx.x * epb;
    for (int i = 0; i < epb; i += 256) {
        int e = base + i + t;
        if (e < E) atomicAdd(&hist[((unsigned)dst[e]) >> 5], 1u);
    }
    __syncthreads();
    for (int i = t; i < NBUCK; i += 256)
        blockhist[(size_t)blockIdx.x * NBUCK + i] = hist[i];
}

// One block (NPBLK=256 threads) per bucket: exclusive scan over the 256
// block counts of this bucket, in place; write the bucket total.
__global__ void k_scanbuck(unsigned int* __restrict__ blockhist,
                           unsigned int* __restrict__ buckettotal) {
    int b = blockIdx.x;
    int t = threadIdx.x;               // 0..255, 4 waves
    int lane = t & 63, wid = t >> 6;
    unsigned int v = blockhist[(size_t)t * NBUCK + b];
    unsigned int x = v;
    #pragma unroll
    for (int off = 1; off < 64; off <<= 1) {
        unsigned int y = __shfl_up(x, off);
        if (lane >= off) x += y;
    }
    __shared__ unsigned int ws[4];
    if (lane == 63) ws[wid] = x;
    __syncthreads();
    if (wid == 0) {                    // full-wave scan of 4 partials
        unsigned int w = (lane < 4) ? ws[lane] : 0u;
        #pragma unroll
        for (int off = 1; off < 4; off <<= 1) {
            unsigned int y = __shfl_up(w, off);
            if (lane >= off) w += y;
        }
        if (lane < 4) ws[lane] = w;
    }
    __syncthreads();
    unsigned int wpre = wid ? ws[wid - 1] : 0u;
    blockhist[(size_t)t * NBUCK + b] = wpre + x - v;   // exclusive prefix
    if (t == 255) buckettotal[b] = wpre + x;           // inclusive total
}

// Single block, 1024 threads, 2 elems/thread: exclusive scan of 2048 totals.
__global__ void k_scantot(const unsigned int* __restrict__ buckettotal,
                          unsigned int* __restrict__ bucketbase) {
    int t = threadIdx.x;
    int lane = t & 63, wid = t >> 6;   // 16 waves
    unsigned int v0 = buckettotal[2 * t], v1 = buckettotal[2 * t + 1];
    unsigned int v = v0 + v1;
    unsigned int x = v;
    #pragma unroll
    for (int off = 1; off < 64; off <<= 1) {
        unsigned int y = __shfl_up(x, off);
        if (lane >= off) x += y;
    }
    __shared__ unsigned int wsum[16];
    if (lane == 63) wsum[wid] = x;
    __syncthreads();
    if (wid == 0) {
        unsigned int w = (lane < 16) ? wsum[lane] : 0u;
        #pragma unroll
        for (int off = 1; off < 16; off <<= 1) {
            unsigned int y = __shfl_up(w, off);
            if (lane >= off) w += y;
        }
        if (lane < 16) wsum[lane] = w;
    }
    __syncthreads();
    unsigned int wpre = wid ? wsum[wid - 1] : 0u;
    unsigned int excl = wpre + x - v;
    bucketbase[2 * t] = excl;
    bucketbase[2 * t + 1] = excl + v0;
}

// Scatter edges into bucket order; pos from LDS cursors (no global atomics).
__global__ void k_partition(const int* __restrict__ src,
                            const int* __restrict__ dst,
                            const unsigned int* __restrict__ blockhist,
                            const unsigned int* __restrict__ bucketbase,
                            unsigned int* __restrict__ pairs, int E, int epb) {
    __shared__ unsigned int cursor[NBUCK];
    int t = threadIdx.x;
    for (int i = t; i < NBUCK; i += 256)
        cursor[i] = bucketbase[i] + blockhist[(size_t)blockIdx.x * NBUCK + i];
    __syncthreads();
    int base = blockIdx.x * epb;
    for (int i = 0; i < epb; i += 256) {
        int e = base + i + t;
        if (e < E) {
            unsigned int d = (unsigned)dst[e];
            unsigned int s = (unsigned)src[e];
            unsigned int pos = atomicAdd(&cursor[d >> 5], 1u);
            pairs[pos] = s | ((d & 31u) << 16);
        }
    }
}

// One block (4 waves) per bucket of 32 nodes. LDS counting sort into per-node
// segments (u16 src), then wave w gathers nodes w*8..w*8+7 with register
// float4 accumulation. BF16=true reads the bf16 staged copy (128 B/edge).
template <bool BF16>
__global__ __launch_bounds__(256) void k_gather3(
        const float* __restrict__ h,          // f32 original (deg==0 fallback)
        const unsigned int* __restrict__ hbf, // bf16 staged copy (2 feat/u32)
        const unsigned int* __restrict__ pairs,
        const unsigned int* __restrict__ bucketbase,
        const unsigned int* __restrict__ buckettotal,
        float* __restrict__ out) {
    __shared__ unsigned int pairbuf[BUCKCAP];
    __shared__ unsigned short ssrc[BUCKCAP];
    __shared__ unsigned int hist[32], offl[32], cur[32];
    int t = threadIdx.x;
    int b = blockIdx.x;
    unsigned int seg = bucketbase[b];
    unsigned int cnt = min(buckettotal[b], (unsigned)BUCKCAP);  // safety clamp

    if (t < 32) hist[t] = 0u;
    __syncthreads();

    for (unsigned int i = t; i < cnt; i += 256u) {
        unsigned int p = pairs[seg + i];
        pairbuf[i] = p;
        atomicAdd(&hist[p >> 16], 1u);
    }
    __syncthreads();

    // Exclusive scan of 32 node counts on wave 0 (full wave, no divergence).
    if (t < 64) {
        unsigned int v = (t < 32) ? hist[t] : 0u;
        unsigned int x = v;
        #pragma unroll
        for (int off = 1; off < 64; off <<= 1) {
            unsigned int y = __shfl_up(x, off);
            if (t >= off) x += y;
        }
        if (t < 32) { offl[t] = x - v; cur[t] = x - v; }
    }
    __syncthreads();

    for (unsigned int i = t; i < cnt; i += 256u) {
        unsigned int p = pairbuf[i];
        unsigned int pos = atomicAdd(&cur[p >> 16], 1u);
        ssrc[pos] = (unsigned short)(p & 0xFFFFu);
    }
    __syncthreads();

    int lane = t & 63, w = t >> 6;
    int egrp = lane >> 4, fq = lane & 15;
    const float4* h4 = (const float4*)h;
    const uint2* h2 = (const uint2*)hbf;
    float4* out4 = (float4*)out;

    for (int ni = 0; ni < 8; ++ni) {
        int n = w * 8 + ni;
        unsigned int start = offl[n];
        unsigned int dg = hist[n];
        float4 acc = make_float4(0.f, 0.f, 0.f, 0.f);
        for (unsigned int base = 0; base < dg; base += 64u) {
            int chunk = (int)min(64u, dg - base);           // wave-uniform
            int sidx = (lane < chunk) ? (int)ssrc[start + base + lane] : 0;
            int nit = (chunk + 3) >> 2;                     // wave-uniform
            for (int it = 0; it < nit; ++it) {
                int j = it * 4 + egrp;
                int s = __shfl(sidx, (j < chunk) ? j : 0);  // all lanes active
                if (BF16) {
                    uint2 m = h2[(size_t)s * 16 + fq];
                    if (j < chunk) {
                        acc.x += __uint_as_float(m.x << 16);
                        acc.y += __uint_as_float(m.x & 0xFFFF0000u);
                        acc.z += __uint_as_float(m.y << 16);
                        acc.w += __uint_as_float(m.y & 0xFFFF0000u);
                    }
                } else {
                    float4 m = h4[(size_t)s * 16 + fq];
                    if (j < chunk) {
                        acc.x += m.x; acc.y += m.y; acc.z += m.z; acc.w += m.w;
                    }
                }
            }
        }
        #pragma unroll
        for (int k = 16; k <= 32; k <<= 1) {
            acc.x += __shfl_xor(acc.x, k);
            acc.y += __shfl_xor(acc.y, k);
            acc.z += __shfl_xor(acc.z, k);
            acc.w += __shfl_xor(acc.w, k);
        }
        if (lane < 16) {
            size_t oi = ((size_t)b * 32 + n) * 16 + fq;
            float4 r;
            if (dg > 0u) {
                float inv = 1.0f / (float)dg;
                r = make_float4(acc.x * inv, acc.y * inv, acc.z * inv, acc.w * inv);
            } else {
                r = h4[oi];               // exact f32 copy
            }
            out4[oi] = r;
        }
    }
}

extern "C" void kernel_launch(void* const* d_in, const int* in_sizes, int n_in,
                              void* d_out, int out_size, void* d_ws, size_t ws_size,
                              hipStream_t stream) {
    const float* h = (const float*)d_in[0];
    const int* src = (const int*)d_in[1];
    const int* dst = (const int*)d_in[2];
    float* out = (float*)d_out;
    int E = in_sizes[1];
    int nodes = out_size / 64;        // 65536

    // ws layout: blockhist 2MB | buckettotal 8KB | bucketbase 8KB | pairs 4MB | hbf 8MB
    unsigned int* blockhist   = (unsigned int*)d_ws;
    unsigned int* buckettotal = blockhist + (size_t)NPBLK * NBUCK;
    unsigned int* bucketbase  = buckettotal + NBUCK;
    unsigned int* pairs       = bucketbase + NBUCK;
    unsigned int* hbf         = pairs + (size_t)E;

    size_t need_base = ((size_t)NPBLK * NBUCK + 2 * NBUCK + (size_t)E) * 4;
    size_t need_bf   = need_base + (size_t)nodes * 64 * 2;
    bool use_bf = (ws_size >= need_bf);

    int epb = ((E + NPBLK - 1) / NPBLK + 255) & ~255;   // edges per edge-pass block

    if (use_bf) {
        int n8 = nodes * 64 / 8;
        k_cvt<<<(n8 + 255) / 256, 256, 0, stream>>>(h, (uint4*)hbf, n8);
    }
    k_hist<<<NPBLK, 256, 0, stream>>>(dst, blockhist, E, epb);
    k_scanbuck<<<NBUCK, NPBLK, 0, stream>>>(blockhist, buckettotal);
    k_scantot<<<1, 1024, 0, stream>>>(buckettotal, bucketbase);
    k_partition<<<NPBLK, 256, 0, stream>>>(src, dst, blockhist, bucketbase, pairs, E, epb);
    if (use_bf)
        k_gather3<true><<<NBUCK, 256, 0, stream>>>(h, hbf, pairs, bucketbase, buckettotal, out);
    else
        k_gather3<false><<<NBUCK, 256, 0, stream>>>(h, hbf, pairs, bucketbase, buckettotal, out);
}

// Round 8
// 52.563 us; speedup vs baseline: 7.4627x; 1.4265x over previous
//
#include <hip/hip_runtime.h>

// GraphPooling: out[v] = mean over in-neighbors of h[src], else h[v] if deg==0.
// 65536 nodes x 64 f32 features, E = 1,048,576 edges.
//
// TWO dispatches, zero global atomics, zero memsets:
//   k_build  : blocks [0,256): partition-local counting sort -- each block owns
//              epb=4096 edges, LDS hist(2048)+scan+scatter into its OWN region
//              of pairs (block-local 16KB writes), u16 offset table out.
//              blocks [256,...): f32 h -> bf16 table (RNE), overlapped.
//   k_gather : block b (of 2048) collects 256 runs via the offset table
//              (block-scan placement), LDS 32-bin sort, wave-per-8-nodes
//              register float4 bf16 gather.
// No cross-block scan chain (rounds 5-7 needed 4 serialized kernels for it).
// Round-5 lesson: no LDS float atomics. Round-3 lesson: wave-uniform shfl.

#define NBUCK 2048     // 32 nodes per bucket
#define NPBLK 256      // partition blocks; epb = E/NPBLK = 4096 (fits u16)
#define NPT   8        // NBUCK / 256 buckets owned per thread in build scan
#define BUCKCAP 1024   // mean 512, sigma ~23 -> 22-sigma headroom

template <bool BF16>
__global__ __launch_bounds__(256) void k_build(
        const float* __restrict__ h,
        const int* __restrict__ src,
        const int* __restrict__ dst,
        unsigned int* __restrict__ pairs,      // [NPBLK * epb]
        unsigned short* __restrict__ offs,     // [NPBLK][NBUCK+1]
        uint4* __restrict__ hbf,               // bf16 table (8 f32 -> 1 uint4)
        int E, int epb, int n8) {
    int t = threadIdx.x;
    int bid = blockIdx.x;

    if (bid >= NPBLK) {
        // ---- cvt part: f32 -> packed bf16 (RNE) ----
        if (!BF16) return;
        int i = (bid - NPBLK) * 256 + t;
        if (i >= n8) return;
        const float4* h4 = (const float4*)h;
        float4 a = h4[2 * i], bq = h4[2 * i + 1];
        auto pk = [](float lo, float hi) {
            unsigned int ul = __float_as_uint(lo), uh = __float_as_uint(hi);
            unsigned int rl = (ul + 0x7FFFu + ((ul >> 16) & 1u)) >> 16;
            unsigned int rh = (uh + 0x7FFFu + ((uh >> 16) & 1u)) & 0xFFFF0000u;
            return rl | rh;
        };
        hbf[i] = make_uint4(pk(a.x, a.y), pk(a.z, a.w), pk(bq.x, bq.y), pk(bq.z, bq.w));
        return;
    }

    // ---- partition part: local counting sort of this block's edge slice ----
    __shared__ unsigned int hist[NBUCK];    // reused as absolute cursors
    __shared__ unsigned int wpart[4];
    for (int i = t; i < NBUCK; i += 256) hist[i] = 0u;
    __syncthreads();

    int base = bid * epb;
    int cnt = E - base; if (cnt > epb) cnt = epb; if (cnt < 0) cnt = 0;

    for (int i = t; i < cnt; i += 256)
        atomicAdd(&hist[((unsigned)dst[base + i]) >> 5], 1u);
    __syncthreads();

    // Block-exclusive scan over 2048 bins; thread t owns bins t*8..t*8+7.
    unsigned int loc[NPT], lsum = 0u;
    #pragma unroll
    for (int i = 0; i < NPT; ++i) { loc[i] = hist[t * NPT + i]; lsum += loc[i]; }
    int lane = t & 63, wid = t >> 6;
    unsigned int x = lsum;
    #pragma unroll
    for (int off = 1; off < 64; off <<= 1) {
        unsigned int y = __shfl_up(x, off);
        if (lane >= off) x += y;
    }
    if (lane == 63) wpart[wid] = x;
    __syncthreads();
    if (wid == 0) {                        // full-wave scan of 4 partials
        unsigned int w = (lane < 4) ? wpart[lane] : 0u;
        #pragma unroll
        for (int off = 1; off < 4; off <<= 1) {
            unsigned int y = __shfl_up(w, off);
            if (lane >= off) w += y;
        }
        if (lane < 4) wpart[lane] = w;
    }
    __syncthreads();
    unsigned int run = (wid ? wpart[wid - 1] : 0u) + x - lsum;

    size_t orow = (size_t)bid * (NBUCK + 1);
    #pragma unroll
    for (int i = 0; i < NPT; ++i) {
        offs[orow + t * NPT + i] = (unsigned short)run;
        hist[t * NPT + i] = (unsigned)base + run;      // absolute cursor
        run += loc[i];
    }
    if (t == 255) offs[orow + NBUCK] = (unsigned short)cnt;
    __syncthreads();

    // Scatter pass: writes confined to this block's [base, base+cnt) region.
    for (int i = t; i < cnt; i += 256) {
        unsigned int d = (unsigned)dst[base + i];
        unsigned int s = (unsigned)src[base + i];
        unsigned int pos = atomicAdd(&hist[d >> 5], 1u);
        pairs[pos] = s | ((d & 31u) << 16);
    }
}

// One block (4 waves) per bucket of 32 nodes.
template <bool BF16>
__global__ __launch_bounds__(256) void k_gather(
        const float* __restrict__ h,          // f32 original (deg==0 fallback)
        const uint2* __restrict__ hbf,        // bf16 table, 16 uint2/node
        const unsigned int* __restrict__ pairs,
        const unsigned short* __restrict__ offs,
        float* __restrict__ out, int epb) {
    __shared__ unsigned int pairbuf[BUCKCAP];
    __shared__ unsigned short ssrc[BUCKCAP];
    __shared__ unsigned int hist[32], offl[32], cur[32];
    __shared__ unsigned int wpart[4];
    int t = threadIdx.x;
    int b = blockIdx.x;
    if (t < 32) hist[t] = 0u;

    // Thread t fetches partition-block t's run bounds for bucket b.
    size_t orow = (size_t)t * (NBUCK + 1);
    unsigned int s0 = offs[orow + b];
    unsigned int s1 = offs[orow + b + 1];
    unsigned int mycnt = s1 - s0;

    // Block scan of run lengths -> placement in pairbuf.
    int lane = t & 63, wid = t >> 6;
    unsigned int x = mycnt;
    #pragma unroll
    for (int off = 1; off < 64; off <<= 1) {
        unsigned int y = __shfl_up(x, off);
        if (lane >= off) x += y;
    }
    if (lane == 63) wpart[wid] = x;
    __syncthreads();                       // also covers hist zero
    if (wid == 0) {
        unsigned int w = (lane < 4) ? wpart[lane] : 0u;
        #pragma unroll
        for (int off = 1; off < 4; off <<= 1) {
            unsigned int y = __shfl_up(w, off);
            if (lane >= off) w += y;
        }
        if (lane < 4) wpart[lane] = w;
    }
    __syncthreads();
    unsigned int mypos = (wid ? wpart[wid - 1] : 0u) + x - mycnt;
    unsigned int cnt = min(wpart[3], (unsigned)BUCKCAP);   // total (clamped)
    if (mypos >= cnt) mycnt = 0u;
    else if (mypos + mycnt > cnt) mycnt = cnt - mypos;

    // Copy my run into pairbuf + per-node LDS hist.
    for (unsigned int k = 0; k < mycnt; ++k) {
        unsigned int pr = pairs[(size_t)t * epb + s0 + k];
        pairbuf[mypos + k] = pr;
        atomicAdd(&hist[pr >> 16], 1u);
    }
    __syncthreads();

    // Exclusive scan of 32 node counts on wave 0 (full wave, no divergence).
    if (t < 64) {
        unsigned int v = (t < 32) ? hist[t] : 0u;
        unsigned int xx = v;
        #pragma unroll
        for (int off = 1; off < 64; off <<= 1) {
            unsigned int y = __shfl_up(xx, off);
            if (t >= off) xx += y;
        }
        if (t < 32) { offl[t] = xx - v; cur[t] = xx - v; }
    }
    __syncthreads();

    // LDS scatter into per-node sorted order (u16 src payload).
    for (unsigned int i = t; i < cnt; i += 256u) {
        unsigned int p = pairbuf[i];
        unsigned int pos = atomicAdd(&cur[p >> 16], 1u);
        ssrc[pos] = (unsigned short)(p & 0xFFFFu);
    }
    __syncthreads();

    // Gather: wave w handles nodes w*8 .. w*8+7.
    int w = t >> 6;
    int egrp = lane >> 4, fq = lane & 15;
    const float4* h4 = (const float4*)h;
    float4* out4 = (float4*)out;

    for (int ni = 0; ni < 8; ++ni) {
        int n = w * 8 + ni;
        unsigned int start = offl[n];
        unsigned int dg = hist[n];
        float4 acc = make_float4(0.f, 0.f, 0.f, 0.f);
        for (unsigned int base = 0; base < dg; base += 64u) {
            int chunk = (int)min(64u, dg - base);           // wave-uniform
            int sidx = (lane < chunk) ? (int)ssrc[start + base + lane] : 0;
            int nit = (chunk + 3) >> 2;                     // wave-uniform
            for (int it = 0; it < nit; ++it) {
                int j = it * 4 + egrp;
                int s = __shfl(sidx, (j < chunk) ? j : 0);  // all lanes active
                if (BF16) {
                    uint2 m = hbf[(size_t)s * 16 + fq];
                    if (j < chunk) {
                        acc.x += __uint_as_float(m.x << 16);
                        acc.y += __uint_as_float(m.x & 0xFFFF0000u);
                        acc.z += __uint_as_float(m.y << 16);
                        acc.w += __uint_as_float(m.y & 0xFFFF0000u);
                    }
                } else {
                    float4 m = h4[(size_t)s * 16 + fq];
                    if (j < chunk) {
                        acc.x += m.x; acc.y += m.y; acc.z += m.z; acc.w += m.w;
                    }
                }
            }
        }
        #pragma unroll
        for (int k = 16; k <= 32; k <<= 1) {
            acc.x += __shfl_xor(acc.x, k);
            acc.y += __shfl_xor(acc.y, k);
            acc.z += __shfl_xor(acc.z, k);
            acc.w += __shfl_xor(acc.w, k);
        }
        if (lane < 16) {
            size_t oi = ((size_t)b * 32 + n) * 16 + fq;
            float4 r;
            if (dg > 0u) {
                float inv = 1.0f / (float)dg;
                r = make_float4(acc.x * inv, acc.y * inv, acc.z * inv, acc.w * inv);
            } else {
                r = h4[oi];               // exact f32 copy
            }
            out4[oi] = r;
        }
    }
}

extern "C" void kernel_launch(void* const* d_in, const int* in_sizes, int n_in,
                              void* d_out, int out_size, void* d_ws, size_t ws_size,
                              hipStream_t stream) {
    const float* h = (const float*)d_in[0];
    const int* src = (const int*)d_in[1];
    const int* dst = (const int*)d_in[2];
    float* out = (float*)d_out;
    int E = in_sizes[1];
    int nodes = out_size / 64;        // 65536

    int epb = ((E + NPBLK - 1) / NPBLK + 255) & ~255;   // 4096 for E=1M

    // ws layout: pairs | offs | hbf  (all 16B-aligned: pairs 4MB, offs 1.049MB)
    unsigned int* pairs  = (unsigned int*)d_ws;                       // NPBLK*epb u32
    unsigned short* offs = (unsigned short*)(pairs + (size_t)NPBLK * epb);
    size_t offs_elems = (size_t)NPBLK * (NBUCK + 1);
    size_t offs_bytes = (offs_elems * 2 + 15) & ~(size_t)15;
    uint4* hbf = (uint4*)((char*)offs + offs_bytes);

    size_t need_base = (size_t)NPBLK * epb * 4 + offs_bytes;
    size_t need_bf   = need_base + (size_t)nodes * 64 * 2;
    bool use_bf = (ws_size >= need_bf);

    int n8 = nodes * 64 / 8;                      // uint4 outputs for cvt
    int cvtblocks = (n8 + 255) / 256;

    if (use_bf) {
        k_build<true><<<NPBLK + cvtblocks, 256, 0, stream>>>(
            h, src, dst, pairs, offs, hbf, E, epb, n8);
        k_gather<true><<<NBUCK, 256, 0, stream>>>(
            h, (const uint2*)hbf, pairs, offs, out, epb);
    } else {
        k_build<false><<<NPBLK, 256, 0, stream>>>(
            h, src, dst, pairs, offs, hbf, E, epb, n8);
        k_gather<false><<<NBUCK, 256, 0, stream>>>(
            h, (const uint2*)hbf, pairs, offs, out, epb);
    }
}